// Round 4
// baseline (481.912 us; speedup 1.0000x reference)
//
#include <hip/hip_runtime.h>
#include <hip/hip_bf16.h>
#include <math.h>

// Problem constants (from reference)
#define B_SZ   128
#define HDIM   256
#define NG     1280     // 5*H
#define NNODES 1023
#define VOCAB  2048

typedef unsigned int uint32;
typedef short  short8v  __attribute__((ext_vector_type(8)));   // 8 x bf16 (4 VGPR)
typedef float  float4v  __attribute__((ext_vector_type(4)));   // MFMA C/D frag

__device__ __forceinline__ float sigm(float x) {
    return 1.0f / (1.0f + __expf(-x));
}
__device__ __forceinline__ float tanh_fast(float x) {
    return 2.0f / (1.0f + __expf(-2.0f * x)) - 1.0f;
}
__device__ __forceinline__ float bf2f(unsigned short u) {
    return __uint_as_float(((uint32)u) << 16);
}
__device__ __forceinline__ unsigned short f2bf(float f) {
    uint32 x = __float_as_uint(f);
    uint32 r = (x + 0x7FFFu + ((x >> 16) & 1u)) >> 16;   // RNE
    return (unsigned short)r;
}

// ---------------------------------------------------------------------------
// EWb = bf16(emb @ Wx + b) : (2048 x 1280), K=256. 64x64 tile fp32 compute.
// ---------------------------------------------------------------------------
__global__ __launch_bounds__(256) void ew_kernel(
    const float* __restrict__ emb, const float* __restrict__ Wx,
    const float* __restrict__ bias, unsigned short* __restrict__ EWb)
{
    __shared__ float As[16][76];
    __shared__ float Bs[16][72];

    const int tid = threadIdx.x;
    const int tx = tid & 15, ty = tid >> 4;
    const int rowBase = blockIdx.x * 64;
    const int colBase = blockIdx.y * 64;

    const int a_rr = tid >> 2, a_kq = tid & 3;
    const int b_kk = tid >> 4, b_c4 = tid & 15;

    float acc[4][4] = {};

    for (int kb = 0; kb < 256; kb += 16) {
        float4 av = *(const float4*)(emb + (size_t)(rowBase + a_rr) * 256 + kb + a_kq * 4);
        float4 bv = *(const float4*)(Wx + (size_t)(kb + b_kk) * NG + colBase + b_c4 * 4);
        __syncthreads();
        As[a_kq * 4 + 0][a_rr] = av.x;
        As[a_kq * 4 + 1][a_rr] = av.y;
        As[a_kq * 4 + 2][a_rr] = av.z;
        As[a_kq * 4 + 3][a_rr] = av.w;
        *(float4*)&Bs[b_kk][b_c4 * 4] = bv;
        __syncthreads();
        #pragma unroll
        for (int k = 0; k < 16; ++k) {
            float4 a = *(const float4*)&As[k][ty * 4];
            float4 b = *(const float4*)&Bs[k][tx * 4];
            acc[0][0] += a.x * b.x; acc[0][1] += a.x * b.y; acc[0][2] += a.x * b.z; acc[0][3] += a.x * b.w;
            acc[1][0] += a.y * b.x; acc[1][1] += a.y * b.y; acc[1][2] += a.y * b.z; acc[1][3] += a.y * b.w;
            acc[2][0] += a.z * b.x; acc[2][1] += a.z * b.y; acc[2][2] += a.z * b.z; acc[2][3] += a.z * b.w;
            acc[3][0] += a.w * b.x; acc[3][1] += a.w * b.y; acc[3][2] += a.w * b.z; acc[3][3] += a.w * b.w;
        }
    }

    #pragma unroll
    for (int u = 0; u < 4; ++u) {
        const int row = rowBase + ty * 4 + u;
        const int col = colBase + tx * 4;
        float4 bb = *(const float4*)(bias + col);
        ushort4 ov;
        ov.x = f2bf(acc[u][0] + bb.x);
        ov.y = f2bf(acc[u][1] + bb.y);
        ov.z = f2bf(acc[u][2] + bb.z);
        ov.w = f2bf(acc[u][3] + bb.w);
        *(ushort4*)(EWb + (size_t)row * NG + col) = ov;
    }
}

// ---------------------------------------------------------------------------
// WTf: fragment-ready bf16 repack of [Ul;Ur] (K=512, N=1280) for MFMA B.
// short8 index = (ng*16 + ks)*64 + lane ; lane = q*16 + c
//   holds B[k = ks*32 + q*8 + j][col = ng*16 + c],  j = 0..7
// ---------------------------------------------------------------------------
__global__ __launch_bounds__(256) void prep_wtf(
    const float* __restrict__ Ul, const float* __restrict__ Ur,
    unsigned short* __restrict__ WTf)
{
    const int t = blockIdx.x * 256 + threadIdx.x;   // 0..81919
    const int l = t & 63;
    const int q = l >> 4, c = l & 15;
    const int ks = (t >> 6) & 15;
    const int ng = t >> 10;                          // 0..79
    const int col = ng * 16 + c;
    const int k = ks * 32 + q * 8;
    const float* src = (k < 256) ? (Ul + (size_t)k * NG + col)
                                 : (Ur + (size_t)(k - 256) * NG + col);
    short8v v;
    #pragma unroll
    for (int j = 0; j < 8; ++j) v[j] = (short)f2bf(src[(size_t)j * NG]);
    *(short8v*)(WTf + (size_t)t * 8) = v;
}

// ---------------------------------------------------------------------------
// Leaf level (d=9): gates = EWb[tok]; c = i*u; h = o*tanh(c).
// ---------------------------------------------------------------------------
__global__ __launch_bounds__(256) void leaf_kernel(
    const unsigned short* __restrict__ EWb, const int* __restrict__ tokens,
    unsigned short* __restrict__ hdst, unsigned short* __restrict__ cdst)
{
    const int r = blockIdx.x;            // 0 .. B*512-1
    const int b = r >> 9, i = r & 511;
    const int node = 511 + i;
    const int tok = tokens[b * NNODES + node];
    const unsigned short* ew = EWb + (size_t)tok * NG;
    const int j = threadIdx.x;

    const float gi = bf2f(ew[j]), go = bf2f(ew[768 + j]), gu = bf2f(ew[1024 + j]);
    const float ii = sigm(gi), oo = sigm(go), uu = tanh_fast(gu);
    const float c = ii * uu;
    const float h = oo * tanh_fast(c);
    const size_t oidx = ((size_t)i * B_SZ + b) * HDIM + j;
    hdst[oidx] = f2bf(h);
    cdst[oidx] = f2bf(c);
}

// ---------------------------------------------------------------------------
// Inner level d (8..0): MFMA bf16 GEMM [hl|hr](Mx512) @ W(512x1280) fused with
// EW gather + LSTM cell.  NO LDS, NO barriers: each lane gathers its A frag
// directly from global (L1/L2-cached, 16x reuse), B frags register-direct
// from frag-ready WTf.  16 K-steps fully unrolled, distance-1 double-buffered
// register prefetch of A and B -> fine-grained vmcnt overlap (no barrier
// drain).  Block: 4 waves; wave w: 64 rows x hcols [y*64+w*16,+16), 5 gates.
// ---------------------------------------------------------------------------
__global__ __launch_bounds__(256) void level_kernel(
    const unsigned short* __restrict__ WTf, const unsigned short* __restrict__ EWb,
    const int* __restrict__ tokens,
    const unsigned short* __restrict__ hsrc, const unsigned short* __restrict__ csrc,
    unsigned short* __restrict__ hdst, unsigned short* __restrict__ cdst,
    float* __restrict__ out, const int d)
{
    const int n = 1 << d;

    const int tid  = threadIdx.x;
    const int lane = tid & 63;
    const int w    = tid >> 6;
    const int quad = lane >> 4, col15 = lane & 15;
    const int rowBase = blockIdx.x * 64;

    // ---- A gather pointers: lane (m=col15, q=quad) -> row rt*16+m, k=q*8+j
    const unsigned short* hlp[4];
    const unsigned short* hrp[4];
    #pragma unroll
    for (int rt = 0; rt < 4; ++rt) {
        const int row = rowBase + rt * 16 + col15;
        const int b = row >> d, i = row & (n - 1);
        hlp[rt] = hsrc + ((size_t)(2 * i)     * B_SZ + b) * HDIM + quad * 8;
        hrp[rt] = hsrc + ((size_t)(2 * i + 1) * B_SZ + b) * HDIM + quad * 8;
    }

    // ---- B pointers: wave w -> h-col tile w; gate g -> ng = g*16 + y*4 + w
    const short8v* bp[5];
    #pragma unroll
    for (int g = 0; g < 5; ++g)
        bp[g] = (const short8v*)WTf + ((size_t)(g * 16 + blockIdx.y * 4 + w) * (16 * 64)) + lane;

    float4v acc[4][5];
    #pragma unroll
    for (int rt = 0; rt < 4; ++rt)
        #pragma unroll
        for (int g = 0; g < 5; ++g)
            #pragma unroll
            for (int e = 0; e < 4; ++e) acc[rt][g][e] = 0.0f;

    short8v abuf[2][4], bbuf[2][5];

    // Preload K-step 0 (kb=0 < 256 -> hl side)
    #pragma unroll
    for (int rt = 0; rt < 4; ++rt) abuf[0][rt] = *(const short8v*)hlp[rt];
    #pragma unroll
    for (int g = 0; g < 5; ++g) bbuf[0][g] = bp[g][0];

    #pragma unroll
    for (int ks = 0; ks < 16; ++ks) {
        const int cur = ks & 1, nxt = cur ^ 1;
        if (ks < 15) {
            const int kn = (ks + 1) * 32;            // next kb
            #pragma unroll
            for (int rt = 0; rt < 4; ++rt) {
                const unsigned short* p = (kn < 256) ? (hlp[rt] + kn) : (hrp[rt] + (kn - 256));
                abuf[nxt][rt] = *(const short8v*)p;
            }
            #pragma unroll
            for (int g = 0; g < 5; ++g) bbuf[nxt][g] = bp[g][(size_t)(ks + 1) * 64];
        }
        #pragma unroll
        for (int rt = 0; rt < 4; ++rt)
            #pragma unroll
            for (int g = 0; g < 5; ++g)
                acc[rt][g] = __builtin_amdgcn_mfma_f32_16x16x32_bf16(
                    abuf[cur][rt], bbuf[cur][g], acc[rt][g], 0, 0, 0);
    }

    // ---- Epilogue: C layout col=lane&15, row=quad*4+reg (verified m89) ----
    const int j = blockIdx.y * 64 + w * 16 + col15;
    #pragma unroll
    for (int rt = 0; rt < 4; ++rt) {
        #pragma unroll
        for (int reg = 0; reg < 4; ++reg) {
            const int row = rowBase + rt * 16 + quad * 4 + reg;
            const int b = row >> d, i = row & (n - 1);
            const int tok = tokens[b * NNODES + (n - 1) + i];
            const unsigned short* ew = EWb + (size_t)tok * NG;
            const float gi  = acc[rt][0][reg] + bf2f(ew[j]);
            const float gfl = acc[rt][1][reg] + bf2f(ew[256 + j]);
            const float gfr = acc[rt][2][reg] + bf2f(ew[512 + j]);
            const float go  = acc[rt][3][reg] + bf2f(ew[768 + j]);
            const float gu  = acc[rt][4][reg] + bf2f(ew[1024 + j]);
            const float cl = bf2f(csrc[((size_t)(2 * i)     * B_SZ + b) * HDIM + j]);
            const float cr = bf2f(csrc[((size_t)(2 * i + 1) * B_SZ + b) * HDIM + j]);
            const float ii = sigm(gi), fl = sigm(gfl), fr = sigm(gfr), oo = sigm(go);
            const float uu = tanh_fast(gu);
            const float c = ii * uu + fl * cl + fr * cr;
            const float h = oo * tanh_fast(c);
            const size_t oidx = ((size_t)i * B_SZ + b) * HDIM + j;
            hdst[oidx] = f2bf(h);
            cdst[oidx] = f2bf(c);
            if (d == 0) out[(size_t)b * HDIM + j] = h;
        }
    }
}

// ---------------------------------------------------------------------------
extern "C" void kernel_launch(void* const* d_in, const int* in_sizes, int n_in,
                              void* d_out, int out_size, void* d_ws, size_t ws_size,
                              hipStream_t stream)
{
    const int*   tokens = (const int*)d_in[0];
    const float* emb    = (const float*)d_in[1];
    const float* Wx     = (const float*)d_in[2];
    const float* Ul     = (const float*)d_in[3];
    const float* Ur     = (const float*)d_in[4];
    const float* bias   = (const float*)d_in[5];
    float* out = (float*)d_out;

    // Workspace: EWb 5.24 MB | WTf 1.31 MB | hA,cA 67.1 MB | hB,cB 33.6 MB = 107.2 MB
    const size_t EW_ELEMS  = (size_t)VOCAB * NG;          // bf16
    const size_t WTF_ELEMS = (size_t)80 * 16 * 64 * 8;    // bf16
    const size_t SLOT_A    = (size_t)512 * B_SZ * HDIM;   // bf16 elements
    const size_t SLOT_B    = (size_t)256 * B_SZ * HDIM;
    const size_t REQUIRED  = (EW_ELEMS + WTF_ELEMS + 2 * (SLOT_A + SLOT_B)) * 2;
    if (ws_size < REQUIRED || d_ws == nullptr) return;    // clean fail, not a fault

    char* ws = (char*)d_ws;
    unsigned short* EWb = (unsigned short*)ws;
    unsigned short* WTf = EWb + EW_ELEMS;
    unsigned short* hA  = WTf + WTF_ELEMS;
    unsigned short* cA  = hA + SLOT_A;
    unsigned short* hB  = cA + SLOT_A;
    unsigned short* cB  = hB + SLOT_B;

    ew_kernel<<<dim3(VOCAB / 64, NG / 64), 256, 0, stream>>>(emb, Wx, bias, EWb);
    prep_wtf<<<dim3(320), 256, 0, stream>>>(Ul, Ur, WTf);
    leaf_kernel<<<dim3(B_SZ * 512), 256, 0, stream>>>(EWb, tokens, hA, cA);

    for (int d = 8; d >= 0; --d) {
        const int M = B_SZ << d;
        const bool evenD = ((d & 1) == 0);
        const unsigned short* hs = evenD ? hA : hB;
        const unsigned short* cs = evenD ? cA : cB;
        unsigned short* hd = evenD ? hB : hA;
        unsigned short* cd = evenD ? cB : cA;
        level_kernel<<<dim3(M / 64, 4), 256, 0, stream>>>(
            WTf, EWb, tokens, hs, cs, hd, cd, out, d);
    }
}

// Round 5
// 446.545 us; speedup vs baseline: 1.0792x; 1.0792x over previous
//
#include <hip/hip_runtime.h>
#include <hip/hip_bf16.h>
#include <math.h>

// Problem constants (from reference)
#define B_SZ   128
#define HDIM   256
#define NG     1280     // 5*H
#define NNODES 1023
#define VOCAB  2048

typedef unsigned int uint32;
typedef short  short8v  __attribute__((ext_vector_type(8)));   // 8 x bf16 (4 VGPR)
typedef float  float4v  __attribute__((ext_vector_type(4)));   // MFMA C/D frag

__device__ __forceinline__ float sigm(float x) {
    return 1.0f / (1.0f + __expf(-x));
}
__device__ __forceinline__ float tanh_fast(float x) {
    return 2.0f / (1.0f + __expf(-2.0f * x)) - 1.0f;
}
__device__ __forceinline__ float bf2f(unsigned short u) {
    return __uint_as_float(((uint32)u) << 16);
}
__device__ __forceinline__ unsigned short f2bf(float f) {
    uint32 x = __float_as_uint(f);
    uint32 r = (x + 0x7FFFu + ((x >> 16) & 1u)) >> 16;   // RNE
    return (unsigned short)r;
}

// ---------------------------------------------------------------------------
// EWb = bf16(emb @ Wx + b) : (2048 x 1280), K=256. 64x64 tile fp32 compute.
// ---------------------------------------------------------------------------
__global__ __launch_bounds__(256) void ew_kernel(
    const float* __restrict__ emb, const float* __restrict__ Wx,
    const float* __restrict__ bias, unsigned short* __restrict__ EWb)
{
    __shared__ float As[16][76];
    __shared__ float Bs[16][72];

    const int tid = threadIdx.x;
    const int tx = tid & 15, ty = tid >> 4;
    const int rowBase = blockIdx.x * 64;
    const int colBase = blockIdx.y * 64;

    const int a_rr = tid >> 2, a_kq = tid & 3;
    const int b_kk = tid >> 4, b_c4 = tid & 15;

    float acc[4][4] = {};

    for (int kb = 0; kb < 256; kb += 16) {
        float4 av = *(const float4*)(emb + (size_t)(rowBase + a_rr) * 256 + kb + a_kq * 4);
        float4 bv = *(const float4*)(Wx + (size_t)(kb + b_kk) * NG + colBase + b_c4 * 4);
        __syncthreads();
        As[a_kq * 4 + 0][a_rr] = av.x;
        As[a_kq * 4 + 1][a_rr] = av.y;
        As[a_kq * 4 + 2][a_rr] = av.z;
        As[a_kq * 4 + 3][a_rr] = av.w;
        *(float4*)&Bs[b_kk][b_c4 * 4] = bv;
        __syncthreads();
        #pragma unroll
        for (int k = 0; k < 16; ++k) {
            float4 a = *(const float4*)&As[k][ty * 4];
            float4 b = *(const float4*)&Bs[k][tx * 4];
            acc[0][0] += a.x * b.x; acc[0][1] += a.x * b.y; acc[0][2] += a.x * b.z; acc[0][3] += a.x * b.w;
            acc[1][0] += a.y * b.x; acc[1][1] += a.y * b.y; acc[1][2] += a.y * b.z; acc[1][3] += a.y * b.w;
            acc[2][0] += a.z * b.x; acc[2][1] += a.z * b.y; acc[2][2] += a.z * b.z; acc[2][3] += a.z * b.w;
            acc[3][0] += a.w * b.x; acc[3][1] += a.w * b.y; acc[3][2] += a.w * b.z; acc[3][3] += a.w * b.w;
        }
    }

    #pragma unroll
    for (int u = 0; u < 4; ++u) {
        const int row = rowBase + ty * 4 + u;
        const int col = colBase + tx * 4;
        float4 bb = *(const float4*)(bias + col);
        ushort4 ov;
        ov.x = f2bf(acc[u][0] + bb.x);
        ov.y = f2bf(acc[u][1] + bb.y);
        ov.z = f2bf(acc[u][2] + bb.z);
        ov.w = f2bf(acc[u][3] + bb.w);
        *(ushort4*)(EWb + (size_t)row * NG + col) = ov;
    }
}

// ---------------------------------------------------------------------------
// WTf: fragment-ready bf16 repack of [Ul;Ur] (K=512, N=1280) for MFMA B.
// short8 index = (ng*16 + ks)*64 + lane ; lane = q*16 + c
//   holds B[k = ks*32 + q*8 + j][col = ng*16 + c],  j = 0..7
// ---------------------------------------------------------------------------
__global__ __launch_bounds__(256) void prep_wtf(
    const float* __restrict__ Ul, const float* __restrict__ Ur,
    unsigned short* __restrict__ WTf)
{
    const int t = blockIdx.x * 256 + threadIdx.x;   // 0..81919
    const int l = t & 63;
    const int q = l >> 4, c = l & 15;
    const int ks = (t >> 6) & 15;
    const int ng = t >> 10;                          // 0..79
    const int col = ng * 16 + c;
    const int k = ks * 32 + q * 8;
    const float* src = (k < 256) ? (Ul + (size_t)k * NG + col)
                                 : (Ur + (size_t)(k - 256) * NG + col);
    short8v v;
    #pragma unroll
    for (int j = 0; j < 8; ++j) v[j] = (short)f2bf(src[(size_t)j * NG]);
    *(short8v*)(WTf + (size_t)t * 8) = v;
}

// ---------------------------------------------------------------------------
// Leaf level (d=9): gates = EWb[tok]; c = i*u; h = o*tanh(c).
// ---------------------------------------------------------------------------
__global__ __launch_bounds__(256) void leaf_kernel(
    const unsigned short* __restrict__ EWb, const int* __restrict__ tokens,
    unsigned short* __restrict__ hdst, unsigned short* __restrict__ cdst)
{
    const int r = blockIdx.x;            // 0 .. B*512-1
    const int b = r >> 9, i = r & 511;
    const int node = 511 + i;
    const int tok = tokens[b * NNODES + node];
    const unsigned short* ew = EWb + (size_t)tok * NG;
    const int j = threadIdx.x;

    const float gi = bf2f(ew[j]), go = bf2f(ew[768 + j]), gu = bf2f(ew[1024 + j]);
    const float ii = sigm(gi), oo = sigm(go), uu = tanh_fast(gu);
    const float c = ii * uu;
    const float h = oo * tanh_fast(c);
    const size_t oidx = ((size_t)i * B_SZ + b) * HDIM + j;
    hdst[oidx] = f2bf(h);
    cdst[oidx] = f2bf(c);
}

// ---------------------------------------------------------------------------
// Inner level d (8..0): MFMA bf16 GEMM [hl|hr](Mx512) @ W(512x1280) fused with
// EW gather + LSTM cell.
//   K-loop: no LDS/barriers; A gathered per-lane from global (L1/L2 reuse),
//           B register-direct from frag-ready WTf; dist-1 register dbuf.
//   Epilogue: ALL scattered operands (EWb rows, child c) cooperatively staged
//           into LDS with 16B vector loads (swizzled, conflict-free), cell
//           computed from LDS, h/c re-staged through LDS and written with
//           coalesced 16B stores.  (Round-4 postmortem: per-lane scalar
//           gathers in the epilogue were the real bottleneck, not the K-loop.)
// Grid: (4 col-tiles, M/64 row-tiles) -> blocks sharing an A-tile are
//       dispatch-adjacent (A fetched from HBM ~once, round-4 was ~4x).
// ---------------------------------------------------------------------------
__global__ __launch_bounds__(256) void level_kernel(
    const unsigned short* __restrict__ WTf, const unsigned short* __restrict__ EWb,
    const int* __restrict__ tokens,
    const unsigned short* __restrict__ hsrc, const unsigned short* __restrict__ csrc,
    unsigned short* __restrict__ hdst, unsigned short* __restrict__ cdst,
    float* __restrict__ out, const int d)
{
    const int n = 1 << d;

    __shared__ int toks[64];
    __shared__ __align__(16) unsigned short ews[5 * 64 * 64];  // 40 KB (reused for h/c writeback)
    __shared__ __align__(16) unsigned short cst[128 * 64];     // 16 KB child c

    const int tid  = threadIdx.x;
    const int lane = tid & 63;
    const int w    = tid >> 6;
    const int quad = lane >> 4, col15 = lane & 15;
    const int jtile   = blockIdx.x;            // 0..3 (fastest-varying)
    const int rowBase = blockIdx.y * 64;
    const int jbase   = jtile * 64;

    // ---- token stage (consumed after the post-K-loop barrier) ----
    if (tid < 64) {
        const int row = rowBase + tid;
        const int b = row >> d, i = row & (n - 1);
        toks[tid] = tokens[b * NNODES + (n - 1) + i];
    }

    // ---- A gather pointers: lane (m=col15, q=quad) -> row rt*16+m, k=q*8+j
    const unsigned short* hlp[4];
    const unsigned short* hrp[4];
    #pragma unroll
    for (int rt = 0; rt < 4; ++rt) {
        const int row = rowBase + rt * 16 + col15;
        const int b = row >> d, i = row & (n - 1);
        hlp[rt] = hsrc + ((size_t)(2 * i)     * B_SZ + b) * HDIM + quad * 8;
        hrp[rt] = hsrc + ((size_t)(2 * i + 1) * B_SZ + b) * HDIM + quad * 8;
    }

    // ---- B pointers: wave w + col-tile -> ng = g*16 + jtile*4 + w ----
    const short8v* bp[5];
    #pragma unroll
    for (int g = 0; g < 5; ++g)
        bp[g] = (const short8v*)WTf + ((size_t)(g * 16 + jtile * 4 + w) * (16 * 64)) + lane;

    float4v acc[4][5];
    #pragma unroll
    for (int rt = 0; rt < 4; ++rt)
        #pragma unroll
        for (int g = 0; g < 5; ++g)
            #pragma unroll
            for (int e = 0; e < 4; ++e) acc[rt][g][e] = 0.0f;

    short8v abuf[2][4], bbuf[2][5];

    #pragma unroll
    for (int rt = 0; rt < 4; ++rt) abuf[0][rt] = *(const short8v*)hlp[rt];
    #pragma unroll
    for (int g = 0; g < 5; ++g) bbuf[0][g] = bp[g][0];

    #pragma unroll
    for (int ks = 0; ks < 16; ++ks) {
        const int cur = ks & 1, nxt = cur ^ 1;
        if (ks < 15) {
            const int kn = (ks + 1) * 32;
            #pragma unroll
            for (int rt = 0; rt < 4; ++rt) {
                const unsigned short* p = (kn < 256) ? (hlp[rt] + kn) : (hrp[rt] + (kn - 256));
                abuf[nxt][rt] = *(const short8v*)p;
            }
            #pragma unroll
            for (int g = 0; g < 5; ++g) bbuf[nxt][g] = bp[g][(size_t)(ks + 1) * 64];
        }
        #pragma unroll
        for (int rt = 0; rt < 4; ++rt)
            #pragma unroll
            for (int g = 0; g < 5; ++g)
                acc[rt][g] = __builtin_amdgcn_mfma_f32_16x16x32_bf16(
                    abuf[cur][rt], bbuf[cur][g], acc[rt][g], 0, 0, 0);
    }

    __syncthreads();    // toks visible; K-loop done block-wide

    // ---- Stage EWb rows: 5 gates x 64 rows x 8 chunks(16B), 10 chunks/thread.
    // Swizzle: chunk u stored at (u + 2*((row>>2)&3)) & 7  (32B rotate / quad).
    #pragma unroll
    for (int k = 0; k < 10; ++k) {
        const int c = tid + k * 256;
        const uint32 row = (uint32)c / 40u;
        const int rem = c - (int)row * 40;
        const int g = rem >> 3, u = rem & 7;
        const int tok = toks[row];
        const short8v v = *(const short8v*)(EWb + (size_t)tok * NG + g * 256 + jbase + u * 8);
        const int ru = (u + 2 * ((row >> 2) & 3)) & 7;
        *(short8v*)(ews + ((g * 64 + row) * 64 + ru * 8)) = v;
    }
    // ---- Stage child c: 64 rows x 2 sides x 8 chunks, 4 chunks/thread ----
    #pragma unroll
    for (int k = 0; k < 4; ++k) {
        const int c = tid + k * 256;
        const int rr = c >> 4, side = (c >> 3) & 1, u = c & 7;
        const int row = rowBase + rr;
        const int b = row >> d, i = row & (n - 1);
        const short8v v = *(const short8v*)(csrc +
            ((size_t)(2 * i + side) * B_SZ + b) * HDIM + jbase + u * 8);
        const int ru = (u + 2 * ((rr >> 2) & 3)) & 7;
        *(short8v*)(cst + (rr * 128 + side * 64 + ru * 8)) = v;
    }
    __syncthreads();

    // ---- Cell math from LDS (C layout: col=lane&15, row=quad*4+reg) ----
    const int jl = w * 16 + col15;              // 0..63 within the col tile
    const int jchunk = jl >> 3, jpos = jl & 7;
    float hv[4][4], cv[4][4];
    #pragma unroll
    for (int rt = 0; rt < 4; ++rt) {
        #pragma unroll
        for (int reg = 0; reg < 4; ++reg) {
            const int rr = rt * 16 + quad * 4 + reg;
            const int roff = ((jchunk + 2 * quad) & 7) * 8 + jpos;  // (rr>>2)&3 == quad
            const float gi  = acc[rt][0][reg] + bf2f(ews[(0 * 64 + rr) * 64 + roff]);
            const float gfl = acc[rt][1][reg] + bf2f(ews[(1 * 64 + rr) * 64 + roff]);
            const float gfr = acc[rt][2][reg] + bf2f(ews[(2 * 64 + rr) * 64 + roff]);
            const float go  = acc[rt][3][reg] + bf2f(ews[(3 * 64 + rr) * 64 + roff]);
            const float gu  = acc[rt][4][reg] + bf2f(ews[(4 * 64 + rr) * 64 + roff]);
            const float cl  = bf2f(cst[rr * 128 +      roff]);
            const float cr  = bf2f(cst[rr * 128 + 64 + roff]);
            const float ii = sigm(gi), fl = sigm(gfl), fr = sigm(gfr), oo = sigm(go);
            const float uu = tanh_fast(gu);
            const float c = ii * uu + fl * cl + fr * cr;
            const float h = oo * tanh_fast(c);
            cv[rt][reg] = c; hv[rt][reg] = h;
            if (d == 0) {
                const int row = rowBase + rr;           // n==1 -> b=row
                out[(size_t)row * HDIM + jbase + jl] = h;
            }
        }
    }

    __syncthreads();    // all ews/cst reads done; reuse ews as h/c writeback buf

    // ---- Write h/c into LDS (same swizzle), then coalesced 16B stores ----
    #pragma unroll
    for (int rt = 0; rt < 4; ++rt) {
        #pragma unroll
        for (int reg = 0; reg < 4; ++reg) {
            const int rr = rt * 16 + quad * 4 + reg;
            const int roff = ((jchunk + 2 * quad) & 7) * 8 + jpos;
            ews[rr * 64 + roff]        = f2bf(hv[rt][reg]);
            ews[4096 + rr * 64 + roff] = f2bf(cv[rt][reg]);
        }
    }
    __syncthreads();

    #pragma unroll
    for (int k = 0; k < 4; ++k) {
        const int c = tid + k * 256;                 // 0..1023
        const int arr = c >> 9, rr = (c >> 3) & 63, u = c & 7;
        const int ru = (u + 2 * ((rr >> 2) & 3)) & 7;
        const short8v v = *(const short8v*)(ews + (arr * 4096 + rr * 64 + ru * 8));
        const int row = rowBase + rr;
        const int b = row >> d, i = row & (n - 1);
        unsigned short* dstp = (arr ? cdst : hdst) +
            ((size_t)i * B_SZ + b) * HDIM + jbase + u * 8;
        *(short8v*)dstp = v;
    }
}

// ---------------------------------------------------------------------------
extern "C" void kernel_launch(void* const* d_in, const int* in_sizes, int n_in,
                              void* d_out, int out_size, void* d_ws, size_t ws_size,
                              hipStream_t stream)
{
    const int*   tokens = (const int*)d_in[0];
    const float* emb    = (const float*)d_in[1];
    const float* Wx     = (const float*)d_in[2];
    const float* Ul     = (const float*)d_in[3];
    const float* Ur     = (const float*)d_in[4];
    const float* bias   = (const float*)d_in[5];
    float* out = (float*)d_out;

    // Workspace: EWb 5.24 MB | WTf 1.31 MB | hA,cA 67.1 MB | hB,cB 33.6 MB = 107.2 MB
    const size_t EW_ELEMS  = (size_t)VOCAB * NG;          // bf16
    const size_t WTF_ELEMS = (size_t)80 * 16 * 64 * 8;    // bf16
    const size_t SLOT_A    = (size_t)512 * B_SZ * HDIM;   // bf16 elements
    const size_t SLOT_B    = (size_t)256 * B_SZ * HDIM;
    const size_t REQUIRED  = (EW_ELEMS + WTF_ELEMS + 2 * (SLOT_A + SLOT_B)) * 2;
    if (ws_size < REQUIRED || d_ws == nullptr) return;    // clean fail, not a fault

    char* ws = (char*)d_ws;
    unsigned short* EWb = (unsigned short*)ws;
    unsigned short* WTf = EWb + EW_ELEMS;
    unsigned short* hA  = WTf + WTF_ELEMS;
    unsigned short* cA  = hA + SLOT_A;
    unsigned short* hB  = cA + SLOT_A;
    unsigned short* cB  = hB + SLOT_B;

    ew_kernel<<<dim3(VOCAB / 64, NG / 64), 256, 0, stream>>>(emb, Wx, bias, EWb);
    prep_wtf<<<dim3(320), 256, 0, stream>>>(Ul, Ur, WTf);
    leaf_kernel<<<dim3(B_SZ * 512), 256, 0, stream>>>(EWb, tokens, hA, cA);

    for (int d = 8; d >= 0; --d) {
        const int M = B_SZ << d;
        const bool evenD = ((d & 1) == 0);
        const unsigned short* hs = evenD ? hA : hB;
        const unsigned short* cs = evenD ? cA : cB;
        unsigned short* hd = evenD ? hB : hA;
        unsigned short* cd = evenD ? cB : cA;
        level_kernel<<<dim3(4, M / 64), 256, 0, stream>>>(
            WTf, EWb, tokens, hs, cs, hd, cd, out, d);
    }
}